// Round 3
// baseline (274.525 us; speedup 1.0000x reference)
//
#include <hip/hip_runtime.h>
#include <hip/hip_bf16.h>
#include <math.h>

#define B_   256
#define D1_  512
#define T_   256
#define O1_  256
#define O2_  128

typedef __attribute__((ext_vector_type(8))) short bf16x8;
typedef __attribute__((ext_vector_type(4))) float f32x4;

// pack two floats -> two bf16 (RNE) in a u32 (low half = a)
__device__ inline unsigned pk2(float a, float b) {
    __hip_bfloat162 h = __float22bfloat162_rn(make_float2(a, b));
    union { __hip_bfloat162 h; unsigned u; } c; c.h = h; return c.u;
}

// split 4 floats into hi-plane (2 u32) and lo-plane (2 u32)
__device__ inline void split4(float v0, float v1, float v2, float v3,
                              uint2& hp, uint2& lp) {
    unsigned h01 = pk2(v0, v1), h23 = pk2(v2, v3);
    float r0 = v0 - __uint_as_float(h01 << 16);
    float r1 = v1 - __uint_as_float(h01 & 0xFFFF0000u);
    float r2 = v2 - __uint_as_float(h23 << 16);
    float r3 = v3 - __uint_as_float(h23 & 0xFFFF0000u);
    hp.x = h01; hp.y = h23; lp.x = pk2(r0, r1); lp.y = pk2(r2, r3);
}

// split 8 floats (two float4) into hi/lo bf16x8 fragments (in-register)
__device__ inline void split8(float4 a, float4 b, bf16x8& h, bf16x8& l) {
    union { uint2 q[2]; bf16x8 v; } H, L;
    split4(a.x, a.y, a.z, a.w, H.q[0], L.q[0]);
    split4(b.x, b.y, b.z, b.w, H.q[1], L.q[1]);
    h = H.v; l = L.v;
}

// 16B fragment from 72-B-strided staging rows (two ds_read_b64)
__device__ inline bf16x8 ld16(const char* p) {
    union { uint2 a[2]; bf16x8 v; } f;
    f.a[0] = *(const uint2*)p;
    f.a[1] = *(const uint2*)(p + 8);
    return f.v;
}
__device__ inline bf16x8 ldb128(const char* p) { return *(const bf16x8*)p; }

#define MFMA16 __builtin_amdgcn_mfma_f32_16x16x32_bf16

__global__ __launch_bounds__(1024, 4) void tabl_mfma(
    const float* __restrict__ x, const float* __restrict__ W1,
    const float* __restrict__ W, const float* __restrict__ W2,
    const float* __restrict__ alpha, const float* __restrict__ bias,
    float* __restrict__ out)
{
    __shared__ __align__(16) char Eh[64 * 512];        // E-hi, later blended-hi (XOR-swizzled)
    __shared__ __align__(16) char El[64 * 512];        // blended-lo
    __shared__ __align__(16) char Bst[2][2][256 * 72]; // [plane hi/lo][buf][row*72B]
    __shared__ float redm[8][64];
    __shared__ float reds[8][64];

    const int tid    = threadIdx.x;
    const int lane16 = tid & 15;
    const int lg     = (tid >> 4) & 3;
    const int wid    = tid >> 6;          // 0..15
    const int wm     = wid >> 3;          // 0..1
    const int wn     = wid & 7;           // 0..7
    const int rowW   = wm * 32;

    // XCD-aware bijective swizzle (1024 blocks, 8 XCDs)
    int wg = blockIdx.x;
    wg = (wg & 7) * 128 + (wg >> 3);
    const int b     = wg >> 2;
    const int obase = (wg & 3) * 64;

    // staging roles
    const int xs_t  = tid & 255;          // t (or s) row
    const int xs_kq = tid >> 8;           // 0..3: k-octet
    const int stW   = xs_t * 72 + xs_kq * 16;

    // per-lane constant offsets
    const int bB[2]    = { (wn * 32 + lane16) * 72 + lg * 16,
                           (wn * 32 + 16 + lane16) * 72 + lg * 16 };
    const int rA[2]    = { rowW + lane16, rowW + 16 + lane16 };
    const int eBase[2] = { rA[0] * 512, rA[1] * 512 };
    const int eSw[2]   = { (rA[0] & 7) << 4, (rA[1] & 7) << 4 };

    // ================= Stage 1: E = W1 @ x[b]  (3-term hi/lo) =================
    f32x4 Eacc[2][2];
    #pragma unroll
    for (int mt = 0; mt < 2; ++mt)
        #pragma unroll
        for (int nt = 0; nt < 2; ++nt) Eacc[mt][nt] = (f32x4){0.f,0.f,0.f,0.f};

    const float* xb = x + (size_t)b * (D1_ * T_) + xs_t;
    { // prologue: chunk 0 -> buf0
        const float* xp = xb + (size_t)(xs_kq * 8) * T_;
        float v[8];
        #pragma unroll
        for (int j = 0; j < 8; ++j) v[j] = xp[(size_t)j * T_];
        uint2 hp, lp;
        split4(v[0],v[1],v[2],v[3],hp,lp);
        *(uint2*)(Bst[0][0] + stW) = hp; *(uint2*)(Bst[1][0] + stW) = lp;
        split4(v[4],v[5],v[6],v[7],hp,lp);
        *(uint2*)(Bst[0][0] + stW + 8) = hp; *(uint2*)(Bst[1][0] + stW + 8) = lp;
    }
    __syncthreads();

    for (int c = 0; c < 16; ++c) {
        const int cur = c & 1;
        float nx[8];
        if (c < 15) {
            const float* xp = xb + (size_t)((c + 1) * 32 + xs_kq * 8) * T_;
            #pragma unroll
            for (int j = 0; j < 8; ++j) nx[j] = xp[(size_t)j * T_];
        }
        // A direct from global (L1/L2-resident), split in-register
        bf16x8 Ah[2], Al[2];
        #pragma unroll
        for (int mt = 0; mt < 2; ++mt) {
            const float4* p = (const float4*)(W1 + (size_t)(obase + rA[mt]) * D1_ + c * 32 + lg * 8);
            split8(p[0], p[1], Ah[mt], Al[mt]);
        }
        bf16x8 Bh[2], Bl[2];
        #pragma unroll
        for (int nt = 0; nt < 2; ++nt) {
            Bh[nt] = ld16(Bst[0][cur] + bB[nt]);
            Bl[nt] = ld16(Bst[1][cur] + bB[nt]);
        }
        #pragma unroll
        for (int mt = 0; mt < 2; ++mt)
            #pragma unroll
            for (int nt = 0; nt < 2; ++nt) {
                Eacc[mt][nt] = MFMA16(Ah[mt], Bh[nt], Eacc[mt][nt], 0,0,0);
                Eacc[mt][nt] = MFMA16(Ah[mt], Bl[nt], Eacc[mt][nt], 0,0,0);
                Eacc[mt][nt] = MFMA16(Al[mt], Bh[nt], Eacc[mt][nt], 0,0,0);
            }
        if (c < 15) {
            uint2 hp, lp;
            split4(nx[0],nx[1],nx[2],nx[3],hp,lp);
            *(uint2*)(Bst[0][cur^1] + stW) = hp; *(uint2*)(Bst[1][cur^1] + stW) = lp;
            split4(nx[4],nx[5],nx[6],nx[7],hp,lp);
            *(uint2*)(Bst[0][cur^1] + stW + 8) = hp; *(uint2*)(Bst[1][cur^1] + stW + 8) = lp;
        }
        __syncthreads();
    }

    // write E-hi to LDS for stage-2 A fragments
    #pragma unroll
    for (int mt = 0; mt < 2; ++mt)
        #pragma unroll
        for (int nt = 0; nt < 2; ++nt)
            #pragma unroll
            for (int i = 0; i < 4; ++i) {
                int r = rowW + mt * 16 + lg * 4 + i;
                int t = wn * 32 + nt * 16 + lane16;
                *(unsigned short*)(Eh + r * 512 + ((2 * t) ^ ((r & 7) << 4))) =
                    (unsigned short)pk2(Eacc[mt][nt][i], 0.f);
            }

    // ================= Stage 2: S = E @ W  (hi-only) =================
    f32x4 Sacc[2][2];
    #pragma unroll
    for (int mt = 0; mt < 2; ++mt)
        #pragma unroll
        for (int nt = 0; nt < 2; ++nt) Sacc[mt][nt] = (f32x4){0.f,0.f,0.f,0.f};

    const float* wb = W + xs_t;
    { // prologue chunk 0 (hi plane only)
        const float* wp = wb + (size_t)(xs_kq * 8) * T_;
        float v[8];
        #pragma unroll
        for (int j = 0; j < 8; ++j) v[j] = wp[(size_t)j * T_];
        uint2 hp;
        hp.x = pk2(v[0], v[1]); hp.y = pk2(v[2], v[3]);
        *(uint2*)(Bst[0][0] + stW) = hp;
        hp.x = pk2(v[4], v[5]); hp.y = pk2(v[6], v[7]);
        *(uint2*)(Bst[0][0] + stW + 8) = hp;
    }
    __syncthreads();

    for (int c = 0; c < 8; ++c) {
        const int cur = c & 1;
        float nx[8];
        if (c < 7) {
            const float* wp = wb + (size_t)((c + 1) * 32 + xs_kq * 8) * T_;
            #pragma unroll
            for (int j = 0; j < 8; ++j) nx[j] = wp[(size_t)j * T_];
        }
        bf16x8 Af[2], Bf[2];
        #pragma unroll
        for (int mt = 0; mt < 2; ++mt)
            Af[mt] = ldb128(Eh + eBase[mt] + ((c * 64 + lg * 16) ^ eSw[mt]));
        #pragma unroll
        for (int nt = 0; nt < 2; ++nt)
            Bf[nt] = ld16(Bst[0][cur] + bB[nt]);
        #pragma unroll
        for (int mt = 0; mt < 2; ++mt)
            #pragma unroll
            for (int nt = 0; nt < 2; ++nt)
                Sacc[mt][nt] = MFMA16(Af[mt], Bf[nt], Sacc[mt][nt], 0,0,0);
        if (c < 7) {
            uint2 hp;
            hp.x = pk2(nx[0], nx[1]); hp.y = pk2(nx[2], nx[3]);
            *(uint2*)(Bst[0][cur^1] + stW) = hp;
            hp.x = pk2(nx[4], nx[5]); hp.y = pk2(nx[6], nx[7]);
            *(uint2*)(Bst[0][cur^1] + stW + 8) = hp;
        }
        __syncthreads();
    }

    // ============ row softmax over s (cross-wave) + blend -> Eh/El ============
    const float a_ = alpha[0];
    f32x4 pex[2][2];
    float pmv[2][4];
    #pragma unroll
    for (int mt = 0; mt < 2; ++mt)
        #pragma unroll
        for (int i = 0; i < 4; ++i) {
            float m = fmaxf(Sacc[mt][0][i], Sacc[mt][1][i]);
            m = fmaxf(m, __shfl_xor(m, 1));
            m = fmaxf(m, __shfl_xor(m, 2));
            m = fmaxf(m, __shfl_xor(m, 4));
            m = fmaxf(m, __shfl_xor(m, 8));
            float p0 = __expf(Sacc[mt][0][i] - m);
            float p1 = __expf(Sacc[mt][1][i] - m);
            pex[mt][0][i] = p0; pex[mt][1][i] = p1;
            float s = p0 + p1;
            s += __shfl_xor(s, 1);
            s += __shfl_xor(s, 2);
            s += __shfl_xor(s, 4);
            s += __shfl_xor(s, 8);
            pmv[mt][i] = m;
            if (lane16 == 0) {
                int r = rowW + mt * 16 + lg * 4 + i;
                redm[wn][r] = m; reds[wn][r] = s;
            }
        }
    __syncthreads();
    #pragma unroll
    for (int mt = 0; mt < 2; ++mt)
        #pragma unroll
        for (int i = 0; i < 4; ++i) {
            int r = rowW + mt * 16 + lg * 4 + i;
            float M = redm[0][r];
            #pragma unroll
            for (int g = 1; g < 8; ++g) M = fmaxf(M, redm[g][r]);
            float den = 0.f;
            #pragma unroll
            for (int g = 0; g < 8; ++g) den += reds[g][r] * __expf(redm[g][r] - M);
            float sc = __expf(pmv[mt][i] - M) / den;
            #pragma unroll
            for (int nt = 0; nt < 2; ++nt) {
                float f = a_ + (1.f - a_) * pex[mt][nt][i] * sc;
                float v = Eacc[mt][nt][i] * f;
                int t = wn * 32 + nt * 16 + lane16;
                unsigned short h = (unsigned short)pk2(v, v);
                float hf = __uint_as_float((unsigned)h << 16);
                unsigned short l = (unsigned short)pk2(v - hf, v - hf);
                int off = r * 512 + ((2 * t) ^ ((r & 7) << 4));
                *(unsigned short*)(Eh + off) = h;
                *(unsigned short*)(El + off) = l;
            }
        }

    // stage-3 prologue: stage W2 chunk 0 (hi+lo)
    const int zs = tid & 127, zq = tid >> 7;
    const int stZ = zs * 72 + zq * 8;
    const float* zb = W2 + zs;
    {
        const float* zp = zb + (size_t)(zq * 4) * O2_;
        float v[4];
        #pragma unroll
        for (int j = 0; j < 4; ++j) v[j] = zp[(size_t)j * O2_];
        uint2 hp, lp;
        split4(v[0], v[1], v[2], v[3], hp, lp);
        *(uint2*)(Bst[0][0] + stZ) = hp;
        *(uint2*)(Bst[1][0] + stZ) = lp;
    }
    __syncthreads();

    // ================= Stage 3: Y = blended @ W2 + bias (3-term) =================
    f32x4 Yacc[2];
    Yacc[0] = (f32x4){0.f,0.f,0.f,0.f};
    Yacc[1] = (f32x4){0.f,0.f,0.f,0.f};
    const int bB3 = (wn * 16 + lane16) * 72 + lg * 16;

    for (int c = 0; c < 8; ++c) {
        const int cur = c & 1;
        float nz[4];
        if (c < 7) {
            const float* zp = zb + (size_t)((c + 1) * 32 + zq * 4) * O2_;
            #pragma unroll
            for (int j = 0; j < 4; ++j) nz[j] = zp[(size_t)j * O2_];
        }
        bf16x8 Afh[2], Afl[2];
        #pragma unroll
        for (int mt = 0; mt < 2; ++mt) {
            int t2 = (c * 64 + lg * 16);
            Afh[mt] = ldb128(Eh + eBase[mt] + (t2 ^ eSw[mt]));
            Afl[mt] = ldb128(El + eBase[mt] + (t2 ^ eSw[mt]));
        }
        bf16x8 Bhf = ld16(Bst[0][cur] + bB3);
        bf16x8 Blf = ld16(Bst[1][cur] + bB3);
        #pragma unroll
        for (int mt = 0; mt < 2; ++mt) {
            Yacc[mt] = MFMA16(Afh[mt], Bhf, Yacc[mt], 0,0,0);
            Yacc[mt] = MFMA16(Afh[mt], Blf, Yacc[mt], 0,0,0);
            Yacc[mt] = MFMA16(Afl[mt], Bhf, Yacc[mt], 0,0,0);
        }
        if (c < 7) {
            uint2 hp, lp;
            split4(nz[0], nz[1], nz[2], nz[3], hp, lp);
            *(uint2*)(Bst[0][cur^1] + stZ) = hp;
            *(uint2*)(Bst[1][cur^1] + stZ) = lp;
        }
        __syncthreads();
    }

    // epilogue: + bias, store pre-softmax Y
    #pragma unroll
    for (int mt = 0; mt < 2; ++mt)
        #pragma unroll
        for (int i = 0; i < 4; ++i) {
            int o  = obase + rowW + mt * 16 + lg * 4 + i;
            int s2 = wn * 16 + lane16;
            out[((size_t)b * O1_ + o) * O2_ + s2] = Yacc[mt][i] + bias[(size_t)o * O2_ + s2];
        }
}

// in-place softmax over axis 1 (O1); one block per batch
__global__ __launch_bounds__(256) void softmax_o1(float* __restrict__ out)
{
    __shared__ float sm[2][128], ss[2][128];
    const int b  = blockIdx.x;
    const int s2 = threadIdx.x & 127;
    const int oh = threadIdx.x >> 7;
    float* p = out + (size_t)b * (O1_ * O2_) + s2;
    float m = -INFINITY, s = 0.f;
    #pragma unroll 4
    for (int o = oh * 128; o < oh * 128 + 128; ++o) {
        float v = p[(size_t)o * O2_];
        float mn = fmaxf(m, v);
        s = s * __expf(m - mn) + __expf(v - mn);
        m = mn;
    }
    sm[oh][s2] = m; ss[oh][s2] = s;
    __syncthreads();
    float M = fmaxf(sm[0][s2], sm[1][s2]);
    float S = ss[0][s2] * __expf(sm[0][s2] - M) + ss[1][s2] * __expf(sm[1][s2] - M);
    float inv = 1.f / S;
    #pragma unroll 4
    for (int o = oh * 128; o < oh * 128 + 128; ++o) {
        float v = p[(size_t)o * O2_];
        p[(size_t)o * O2_] = __expf(v - M) * inv;
    }
}

extern "C" void kernel_launch(void* const* d_in, const int* in_sizes, int n_in,
                              void* d_out, int out_size, void* d_ws, size_t ws_size,
                              hipStream_t stream)
{
    const float* x     = (const float*)d_in[0];
    const float* W1    = (const float*)d_in[1];
    const float* W     = (const float*)d_in[2];
    const float* W2    = (const float*)d_in[3];
    const float* alpha = (const float*)d_in[4];
    const float* bias  = (const float*)d_in[5];
    float* out = (float*)d_out;

    tabl_mfma<<<dim3(1024), 1024, 0, stream>>>(x, W1, W, W2, alpha, bias, out);
    softmax_o1<<<B_, 256, 0, stream>>>(out);
}

// Round 4
// 215.383 us; speedup vs baseline: 1.2746x; 1.2746x over previous
//
#include <hip/hip_runtime.h>
#include <hip/hip_bf16.h>
#include <math.h>

#define B_   256
#define D1_  512
#define T_   256
#define O1_  256
#define O2_  128

typedef __attribute__((ext_vector_type(8))) short bf16x8;
typedef __attribute__((ext_vector_type(4))) float f32x4;

// pack two floats -> two bf16 (RNE) in a u32 (low half = a)
__device__ inline unsigned pk2(float a, float b) {
    __hip_bfloat162 h = __float22bfloat162_rn(make_float2(a, b));
    union { __hip_bfloat162 h; unsigned u; } c; c.h = h; return c.u;
}

// split 4 floats into hi-plane (2 u32) and lo-plane (2 u32)
__device__ inline void split4(float v0, float v1, float v2, float v3,
                              uint2& hp, uint2& lp) {
    unsigned h01 = pk2(v0, v1), h23 = pk2(v2, v3);
    float r0 = v0 - __uint_as_float(h01 << 16);
    float r1 = v1 - __uint_as_float(h01 & 0xFFFF0000u);
    float r2 = v2 - __uint_as_float(h23 << 16);
    float r3 = v3 - __uint_as_float(h23 & 0xFFFF0000u);
    hp.x = h01; hp.y = h23; lp.x = pk2(r0, r1); lp.y = pk2(r2, r3);
}

// 16B fragment from 72-B-strided staging rows (two ds_read_b64)
__device__ inline bf16x8 ld16(const char* p) {
    union { uint2 a[2]; bf16x8 v; } f;
    f.a[0] = *(const uint2*)p;
    f.a[1] = *(const uint2*)(p + 8);
    return f.v;
}
__device__ inline bf16x8 ldb128(const char* p) { return *(const bf16x8*)p; }

#define MFMA16 __builtin_amdgcn_mfma_f32_16x16x32_bf16

// OT=32 o-rows per block, 512 threads (8 waves), 2 blocks/CU (74.5 KB LDS).
__global__ __launch_bounds__(512, 4) void tabl_mfma(
    const float* __restrict__ x, const float* __restrict__ W1,
    const float* __restrict__ W, const float* __restrict__ W2,
    const float* __restrict__ alpha, const float* __restrict__ bias,
    float* __restrict__ out)
{
    __shared__ __align__(16) char Eh[32 * 512];      // E-hi / blended-hi (XOR-swizzled rows)
    __shared__ __align__(16) char El[32 * 512];      // blended-lo
    __shared__ __align__(16) char Bst[2][256 * 72];  // B staging [plane hi/lo]
    __shared__ __align__(16) char Ast[2][32 * 72];   // W1 staging [plane hi/lo]
    __shared__ float redm[8][32];
    __shared__ float reds[8][32];

    const int tid    = threadIdx.x;
    const int lane16 = tid & 15;
    const int lg     = (tid >> 4) & 3;
    const int wid    = tid >> 6;          // 0..7

    // XCD-aware bijective swizzle: 2048 blocks, 8 XCDs; one batch's 8 o-tiles
    // land on the same XCD (x[b] L2 locality).
    int wg = blockIdx.x;
    wg = (wg & 7) * 256 + (wg >> 3);
    const int b     = wg >> 3;
    const int obase = (wg & 7) * 32;

    // staging roles (B tiles: 256 rows x 32 k per chunk)
    const int xs_t  = tid & 255;
    const int xs_kh = tid >> 8;           // 0/1
    const int stW   = xs_t * 72 + xs_kh * 32;

    // per-lane constant offsets
    const int rA[2]    = { lane16, 16 + lane16 };               // A rows (o)
    const int bB[2]    = { (wid * 32 + lane16) * 72 + lg * 16,
                           (wid * 32 + 16 + lane16) * 72 + lg * 16 };
    const int eBase[2] = { rA[0] * 512, rA[1] * 512 };
    const int eSw[2]   = { (rA[0] & 7) << 4, (rA[1] & 7) << 4 };

    // ================= Stage 1: E = W1 @ x[b]  (3-term hi/lo) =================
    f32x4 Eacc[2][2];
    #pragma unroll
    for (int mt = 0; mt < 2; ++mt)
        #pragma unroll
        for (int nt = 0; nt < 2; ++nt) Eacc[mt][nt] = (f32x4){0.f,0.f,0.f,0.f};

    const float* xb = x + (size_t)b * (D1_ * T_) + xs_t;
    const int w1r = tid >> 3, w1k = tid & 7;        // valid when tid<256

    float xa[16]; float4 wa;
    #pragma unroll
    for (int j = 0; j < 16; ++j) xa[j] = xb[(size_t)(xs_kh * 16 + j) * T_];
    if (tid < 256)
        wa = *(const float4*)(W1 + (size_t)(obase + w1r) * D1_ + w1k * 4);

    #pragma unroll 2
    for (int c = 0; c < 16; ++c) {
        float xpf[16]; float4 wpf;
        if (c < 15) {
            #pragma unroll
            for (int j = 0; j < 16; ++j)
                xpf[j] = xb[(size_t)((c + 1) * 32 + xs_kh * 16 + j) * T_];
            if (tid < 256)
                wpf = *(const float4*)(W1 + (size_t)(obase + w1r) * D1_ + (c + 1) * 32 + w1k * 4);
        }
        // convert + transposed write of current chunk
        {
            char* bh = Bst[0] + stW;
            char* bl = Bst[1] + stW;
            #pragma unroll
            for (int q = 0; q < 4; ++q) {
                uint2 hp, lp;
                split4(xa[q*4+0], xa[q*4+1], xa[q*4+2], xa[q*4+3], hp, lp);
                *(uint2*)(bh + q * 8) = hp;
                *(uint2*)(bl + q * 8) = lp;
            }
            if (tid < 256) {
                uint2 hp, lp;
                split4(wa.x, wa.y, wa.z, wa.w, hp, lp);
                *(uint2*)(Ast[0] + w1r * 72 + w1k * 8) = hp;
                *(uint2*)(Ast[1] + w1r * 72 + w1k * 8) = lp;
            }
        }
        __syncthreads();
        {
            bf16x8 Ah[2], Al[2], Bh[2], Bl[2];
            #pragma unroll
            for (int mt = 0; mt < 2; ++mt) {
                Ah[mt] = ld16(Ast[0] + rA[mt] * 72 + lg * 16);
                Al[mt] = ld16(Ast[1] + rA[mt] * 72 + lg * 16);
            }
            #pragma unroll
            for (int nt = 0; nt < 2; ++nt) {
                Bh[nt] = ld16(Bst[0] + bB[nt]);
                Bl[nt] = ld16(Bst[1] + bB[nt]);
            }
            #pragma unroll
            for (int mt = 0; mt < 2; ++mt)
                #pragma unroll
                for (int nt = 0; nt < 2; ++nt) {
                    Eacc[mt][nt] = MFMA16(Ah[mt], Bh[nt], Eacc[mt][nt], 0,0,0);
                    Eacc[mt][nt] = MFMA16(Ah[mt], Bl[nt], Eacc[mt][nt], 0,0,0);
                    Eacc[mt][nt] = MFMA16(Al[mt], Bh[nt], Eacc[mt][nt], 0,0,0);
                }
        }
        __syncthreads();
        if (c < 15) {
            #pragma unroll
            for (int j = 0; j < 16; ++j) xa[j] = xpf[j];
            if (tid < 256) wa = wpf;
        }
    }

    // write E-hi to LDS for stage-2 A fragments (E stays in regs)
    #pragma unroll
    for (int mt = 0; mt < 2; ++mt)
        #pragma unroll
        for (int nt = 0; nt < 2; ++nt)
            #pragma unroll
            for (int i = 0; i < 4; ++i) {
                int r = mt * 16 + lg * 4 + i;
                int t = wid * 32 + nt * 16 + lane16;
                *(unsigned short*)(Eh + r * 512 + ((2 * t) ^ ((r & 7) << 4))) =
                    (unsigned short)pk2(Eacc[mt][nt][i], 0.f);
            }

    // ================= Stage 2: S = E @ W  (hi-only) =================
    f32x4 Sacc[2][2];
    #pragma unroll
    for (int mt = 0; mt < 2; ++mt)
        #pragma unroll
        for (int nt = 0; nt < 2; ++nt) Sacc[mt][nt] = (f32x4){0.f,0.f,0.f,0.f};

    const float* wsrc = W + xs_t;
    float ya[16];
    #pragma unroll
    for (int j = 0; j < 16; ++j) ya[j] = wsrc[(size_t)(xs_kh * 16 + j) * T_];

    #pragma unroll 2
    for (int c = 0; c < 8; ++c) {
        float ypf[16];
        if (c < 7) {
            #pragma unroll
            for (int j = 0; j < 16; ++j)
                ypf[j] = wsrc[(size_t)((c + 1) * 32 + xs_kh * 16 + j) * T_];
        }
        {
            char* bh = Bst[0] + stW;
            #pragma unroll
            for (int q = 0; q < 4; ++q) {
                uint2 hp;
                hp.x = pk2(ya[q*4+0], ya[q*4+1]);
                hp.y = pk2(ya[q*4+2], ya[q*4+3]);
                *(uint2*)(bh + q * 8) = hp;
            }
        }
        __syncthreads();
        {
            bf16x8 Af[2], Bf[2];
            #pragma unroll
            for (int mt = 0; mt < 2; ++mt)
                Af[mt] = ldb128(Eh + eBase[mt] + ((c * 64 + lg * 16) ^ eSw[mt]));
            #pragma unroll
            for (int nt = 0; nt < 2; ++nt)
                Bf[nt] = ld16(Bst[0] + bB[nt]);
            #pragma unroll
            for (int mt = 0; mt < 2; ++mt)
                #pragma unroll
                for (int nt = 0; nt < 2; ++nt)
                    Sacc[mt][nt] = MFMA16(Af[mt], Bf[nt], Sacc[mt][nt], 0,0,0);
        }
        __syncthreads();
        if (c < 7) {
            #pragma unroll
            for (int j = 0; j < 16; ++j) ya[j] = ypf[j];
        }
    }

    // ============ row softmax over s (cross-wave) + blend -> Eh/El ============
    const float a_ = alpha[0];
    f32x4 pex[2][2];
    float pmv[2][4];
    #pragma unroll
    for (int mt = 0; mt < 2; ++mt)
        #pragma unroll
        for (int i = 0; i < 4; ++i) {
            float m = fmaxf(Sacc[mt][0][i], Sacc[mt][1][i]);
            m = fmaxf(m, __shfl_xor(m, 1));
            m = fmaxf(m, __shfl_xor(m, 2));
            m = fmaxf(m, __shfl_xor(m, 4));
            m = fmaxf(m, __shfl_xor(m, 8));
            float p0 = __expf(Sacc[mt][0][i] - m);
            float p1 = __expf(Sacc[mt][1][i] - m);
            pex[mt][0][i] = p0; pex[mt][1][i] = p1;
            float s = p0 + p1;
            s += __shfl_xor(s, 1);
            s += __shfl_xor(s, 2);
            s += __shfl_xor(s, 4);
            s += __shfl_xor(s, 8);
            pmv[mt][i] = m;
            if (lane16 == 0) {
                int r = mt * 16 + lg * 4 + i;
                redm[wid][r] = m; reds[wid][r] = s;
            }
        }
    __syncthreads();
    #pragma unroll
    for (int mt = 0; mt < 2; ++mt)
        #pragma unroll
        for (int i = 0; i < 4; ++i) {
            int r = mt * 16 + lg * 4 + i;
            float M = redm[0][r];
            #pragma unroll
            for (int g = 1; g < 8; ++g) M = fmaxf(M, redm[g][r]);
            float den = 0.f;
            #pragma unroll
            for (int g = 0; g < 8; ++g) den += reds[g][r] * __expf(redm[g][r] - M);
            float sc = __expf(pmv[mt][i] - M) / den;
            #pragma unroll
            for (int nt = 0; nt < 2; ++nt) {
                float f = a_ + (1.f - a_) * pex[mt][nt][i] * sc;
                float v = Eacc[mt][nt][i] * f;
                int t = wid * 32 + nt * 16 + lane16;
                unsigned short h = (unsigned short)pk2(v, v);
                float hf = __uint_as_float((unsigned)h << 16);
                unsigned short l = (unsigned short)pk2(v - hf, v - hf);
                int off = r * 512 + ((2 * t) ^ ((r & 7) << 4));
                *(unsigned short*)(Eh + off) = h;
                *(unsigned short*)(El + off) = l;
            }
        }

    // ================= Stage 3: Y = blended @ W2 + bias (3-term) =================
    f32x4 Yacc[2];
    Yacc[0] = (f32x4){0.f,0.f,0.f,0.f};
    Yacc[1] = (f32x4){0.f,0.f,0.f,0.f};

    const int zs = tid & 127, zq = tid >> 7;     // s2 row, k-quarter (8 k each)
    const int stZ = zs * 72 + zq * 16;
    const float* zb = W2 + zs;
    const int bB3 = (wid * 16 + lane16) * 72 + lg * 16;

    float za[8];
    #pragma unroll
    for (int j = 0; j < 8; ++j) za[j] = zb[(size_t)(zq * 8 + j) * O2_];

    #pragma unroll 2
    for (int c = 0; c < 8; ++c) {
        float zpf[8];
        if (c < 7) {
            #pragma unroll
            for (int j = 0; j < 8; ++j)
                zpf[j] = zb[(size_t)((c + 1) * 32 + zq * 8 + j) * O2_];
        }
        {
            uint2 hp, lp;
            split4(za[0], za[1], za[2], za[3], hp, lp);
            *(uint2*)(Bst[0] + stZ) = hp;
            *(uint2*)(Bst[1] + stZ) = lp;
            split4(za[4], za[5], za[6], za[7], hp, lp);
            *(uint2*)(Bst[0] + stZ + 8) = hp;
            *(uint2*)(Bst[1] + stZ + 8) = lp;
        }
        __syncthreads();
        {
            bf16x8 Afh[2], Afl[2];
            #pragma unroll
            for (int mt = 0; mt < 2; ++mt) {
                int t2 = (c * 64 + lg * 16);
                Afh[mt] = ldb128(Eh + eBase[mt] + (t2 ^ eSw[mt]));
                Afl[mt] = ldb128(El + eBase[mt] + (t2 ^ eSw[mt]));
            }
            bf16x8 Bhf = ld16(Bst[0] + bB3);
            bf16x8 Blf = ld16(Bst[1] + bB3);
            #pragma unroll
            for (int mt = 0; mt < 2; ++mt) {
                Yacc[mt] = MFMA16(Afh[mt], Bhf, Yacc[mt], 0,0,0);
                Yacc[mt] = MFMA16(Afh[mt], Blf, Yacc[mt], 0,0,0);
                Yacc[mt] = MFMA16(Afl[mt], Bhf, Yacc[mt], 0,0,0);
            }
        }
        __syncthreads();
        if (c < 7) {
            #pragma unroll
            for (int j = 0; j < 8; ++j) za[j] = zpf[j];
        }
    }

    // epilogue: + bias, store pre-softmax Y
    #pragma unroll
    for (int mt = 0; mt < 2; ++mt)
        #pragma unroll
        for (int i = 0; i < 4; ++i) {
            int o  = obase + mt * 16 + lg * 4 + i;
            int s2 = wid * 16 + lane16;
            out[((size_t)b * O1_ + o) * O2_ + s2] = Yacc[mt][i] + bias[(size_t)o * O2_ + s2];
        }
}

// in-place softmax over axis 1 (O1); one block per batch
__global__ __launch_bounds__(256) void softmax_o1(float* __restrict__ out)
{
    __shared__ float sm[2][128], ss[2][128];
    const int b  = blockIdx.x;
    const int s2 = threadIdx.x & 127;
    const int oh = threadIdx.x >> 7;
    float* p = out + (size_t)b * (O1_ * O2_) + s2;
    float m = -INFINITY, s = 0.f;
    #pragma unroll 4
    for (int o = oh * 128; o < oh * 128 + 128; ++o) {
        float v = p[(size_t)o * O2_];
        float mn = fmaxf(m, v);
        s = s * __expf(m - mn) + __expf(v - mn);
        m = mn;
    }
    sm[oh][s2] = m; ss[oh][s2] = s;
    __syncthreads();
    float M = fmaxf(sm[0][s2], sm[1][s2]);
    float S = ss[0][s2] * __expf(sm[0][s2] - M) + ss[1][s2] * __expf(sm[1][s2] - M);
    float inv = 1.f / S;
    #pragma unroll 4
    for (int o = oh * 128; o < oh * 128 + 128; ++o) {
        float v = p[(size_t)o * O2_];
        p[(size_t)o * O2_] = __expf(v - M) * inv;
    }
}

extern "C" void kernel_launch(void* const* d_in, const int* in_sizes, int n_in,
                              void* d_out, int out_size, void* d_ws, size_t ws_size,
                              hipStream_t stream)
{
    const float* x     = (const float*)d_in[0];
    const float* W1    = (const float*)d_in[1];
    const float* W     = (const float*)d_in[2];
    const float* W2    = (const float*)d_in[3];
    const float* alpha = (const float*)d_in[4];
    const float* bias  = (const float*)d_in[5];
    float* out = (float*)d_out;

    tabl_mfma<<<dim3(2048), 512, 0, stream>>>(x, W1, W, W2, alpha, bias, out);
    softmax_o1<<<B_, 256, 0, stream>>>(out);
}

// Round 5
// 142.890 us; speedup vs baseline: 1.9212x; 1.5073x over previous
//
#include <hip/hip_runtime.h>
#include <hip/hip_bf16.h>
#include <math.h>

#define B_   256
#define D1_  512
#define T_   256
#define O1_  256
#define O2_  128
#define OT   128

typedef __attribute__((ext_vector_type(8))) short bf16x8;
typedef __attribute__((ext_vector_type(4))) float f32x4;

// pack two floats -> two bf16 (RNE) in a u32 (low half = a)
__device__ inline unsigned pk2(float a, float b) {
    __hip_bfloat162 h = __float22bfloat162_rn(make_float2(a, b));
    union { __hip_bfloat162 h; unsigned u; } c; c.h = h; return c.u;
}

// split 4 floats into hi-plane (2 u32) and lo-plane (2 u32)
__device__ inline void split4(float v0, float v1, float v2, float v3,
                              uint2& hp, uint2& lp) {
    unsigned h01 = pk2(v0, v1), h23 = pk2(v2, v3);
    float r0 = v0 - __uint_as_float(h01 << 16);
    float r1 = v1 - __uint_as_float(h01 & 0xFFFF0000u);
    float r2 = v2 - __uint_as_float(h23 << 16);
    float r3 = v3 - __uint_as_float(h23 & 0xFFFF0000u);
    hp.x = h01; hp.y = h23; lp.x = pk2(r0, r1); lp.y = pk2(r2, r3);
}

// split 8 floats (two float4) into hi/lo bf16x8 fragments (in-register, for A)
__device__ inline void split8(float4 a, float4 b, bf16x8& h, bf16x8& l) {
    union { uint2 q[2]; bf16x8 v; } H, L;
    split4(a.x, a.y, a.z, a.w, H.q[0], L.q[0]);
    split4(b.x, b.y, b.z, b.w, H.q[1], L.q[1]);
    h = H.v; l = L.v;
}

// 16B fragment from 72-B-strided staging rows (two ds_read_b64)
__device__ inline bf16x8 ld16(const char* p) {
    union { uint2 a[2]; bf16x8 v; } f;
    f.a[0] = *(const uint2*)p;
    f.a[1] = *(const uint2*)(p + 8);
    return f.v;
}
__device__ inline bf16x8 ldb128(const char* p) { return *(const bf16x8*)p; }

#define MFMA16 __builtin_amdgcn_mfma_f32_16x16x32_bf16

// OT=128 o-rows per block, 1024 threads (16 waves, 4m x 4n), 1 block/CU,
// double-buffered staging with ONE barrier per K-chunk.
__global__ __launch_bounds__(1024, 4) void tabl_mfma(
    const float* __restrict__ x, const float* __restrict__ W1,
    const float* __restrict__ W, const float* __restrict__ W2,
    const float* __restrict__ alpha, const float* __restrict__ bias,
    float* __restrict__ out)
{
    __shared__ __align__(16) char Eh[OT * 512];        // E-hi / blended-hi, XOR-swizzled
    __shared__ __align__(16) char Bst[2][2][256 * 72]; // [buf][plane hi/lo]
    __shared__ float redm[4][OT];
    __shared__ float reds[4][OT];

    const int tid    = threadIdx.x;
    const int lane16 = tid & 15;
    const int lg     = (tid >> 4) & 3;
    const int wid    = tid >> 6;          // 0..15
    const int wm     = wid >> 2;          // 0..3
    const int wn     = wid & 3;           // 0..3

    // XCD swizzle: both o-halves of a batch land on the same XCD.
    const int bi  = blockIdx.x;
    const int xcd = bi & 7, q = bi >> 3;
    const int b     = xcd + (q >> 1) * 8;
    const int obase = (q & 1) * OT;

    // staging roles
    const int xs_t = tid & 255;           // staged row (t or s)
    const int koct = tid >> 8;            // 0..3 (8 k each)
    const int stO  = xs_t * 72 + koct * 16;
    const int zs = tid & 127, zoct = (tid >> 7) & 7;   // stage-3: 4 t each
    const int stZ  = zs * 72 + zoct * 8;

    // fragment offsets
    const int rArow[2] = { obase + wm * 32 + lane16, obase + wm * 32 + 16 + lane16 };
    const int eR[2]    = { wm * 32 + lane16, wm * 32 + 16 + lane16 };
    const int eBase[2] = { eR[0] * 512, eR[1] * 512 };
    const int eSw[2]   = { (eR[0] & 7) << 4, (eR[1] & 7) << 4 };
    int bOff[4], b3Off[2];
    #pragma unroll
    for (int nt = 0; nt < 4; ++nt) bOff[nt] = (wn * 64 + nt * 16 + lane16) * 72 + lg * 16;
    #pragma unroll
    for (int nt = 0; nt < 2; ++nt) b3Off[nt] = (wn * 32 + nt * 16 + lane16) * 72 + lg * 16;

    // ================= Stage 1: E = W1 @ x[b]  (3-term hi/lo) =================
    f32x4 Eacc[2][4];
    #pragma unroll
    for (int mt = 0; mt < 2; ++mt)
        #pragma unroll
        for (int nt = 0; nt < 4; ++nt) Eacc[mt][nt] = (f32x4){0.f,0.f,0.f,0.f};

    const float* xcol = x + (size_t)b * (D1_ * T_) + xs_t;
    float xr[8]; float4 apf[2][2];

    { // prologue: x chunk 0 -> buf0; A chunk 0 -> regs
        #pragma unroll
        for (int j = 0; j < 8; ++j) xr[j] = xcol[(size_t)(koct * 8 + j) * T_];
        #pragma unroll
        for (int mt = 0; mt < 2; ++mt) {
            const float4* ap = (const float4*)(W1 + (size_t)rArow[mt] * D1_ + lg * 8);
            apf[mt][0] = ap[0]; apf[mt][1] = ap[1];
        }
        uint2 hp, lp;
        split4(xr[0],xr[1],xr[2],xr[3],hp,lp);
        *(uint2*)(Bst[0][0] + stO) = hp; *(uint2*)(Bst[0][1] + stO) = lp;
        split4(xr[4],xr[5],xr[6],xr[7],hp,lp);
        *(uint2*)(Bst[0][0] + stO + 8) = hp; *(uint2*)(Bst[0][1] + stO + 8) = lp;
    }
    __syncthreads();

    #pragma unroll 2
    for (int c = 0; c < 16; ++c) {
        const int cur = c & 1;
        // (1) issue x loads for c+1
        if (c < 15) {
            #pragma unroll
            for (int j = 0; j < 8; ++j)
                xr[j] = xcol[(size_t)((c + 1) * 32 + koct * 8 + j) * T_];
        }
        // (2) split current A regs -> fragments
        bf16x8 Ah[2], Al[2];
        #pragma unroll
        for (int mt = 0; mt < 2; ++mt) split8(apf[mt][0], apf[mt][1], Ah[mt], Al[mt]);
        // (3) issue A loads for c+1
        if (c < 15) {
            #pragma unroll
            for (int mt = 0; mt < 2; ++mt) {
                const float4* ap = (const float4*)(W1 + (size_t)rArow[mt] * D1_ + (c + 1) * 32 + lg * 8);
                apf[mt][0] = ap[0]; apf[mt][1] = ap[1];
            }
        }
        // (4) B fragments + MFMA (nt-paired to limit registers)
        __builtin_amdgcn_s_setprio(1);
        #pragma unroll
        for (int np = 0; np < 2; ++np) {
            bf16x8 Bh[2], Bl[2];
            #pragma unroll
            for (int h = 0; h < 2; ++h) {
                Bh[h] = ld16(Bst[cur][0] + bOff[np * 2 + h]);
                Bl[h] = ld16(Bst[cur][1] + bOff[np * 2 + h]);
            }
            #pragma unroll
            for (int mt = 0; mt < 2; ++mt)
                #pragma unroll
                for (int h = 0; h < 2; ++h) {
                    Eacc[mt][np*2+h] = MFMA16(Ah[mt], Bh[h], Eacc[mt][np*2+h], 0,0,0);
                    Eacc[mt][np*2+h] = MFMA16(Ah[mt], Bl[h], Eacc[mt][np*2+h], 0,0,0);
                    Eacc[mt][np*2+h] = MFMA16(Al[mt], Bh[h], Eacc[mt][np*2+h], 0,0,0);
                }
        }
        __builtin_amdgcn_s_setprio(0);
        // (5) convert + write chunk c+1 into the other buffer
        if (c < 15) {
            uint2 hp, lp;
            split4(xr[0],xr[1],xr[2],xr[3],hp,lp);
            *(uint2*)(Bst[cur^1][0] + stO) = hp; *(uint2*)(Bst[cur^1][1] + stO) = lp;
            split4(xr[4],xr[5],xr[6],xr[7],hp,lp);
            *(uint2*)(Bst[cur^1][0] + stO + 8) = hp; *(uint2*)(Bst[cur^1][1] + stO + 8) = lp;
        }
        __syncthreads();
    }

    // write E-hi to LDS for stage-2/3 A fragments (E stays in regs for blend)
    #pragma unroll
    for (int mt = 0; mt < 2; ++mt)
        #pragma unroll
        for (int nt = 0; nt < 4; ++nt)
            #pragma unroll
            for (int i = 0; i < 4; ++i) {
                int r = wm * 32 + mt * 16 + lg * 4 + i;
                int t = wn * 64 + nt * 16 + lane16;
                *(unsigned short*)(Eh + r * 512 + ((2 * t) ^ ((r & 7) << 4))) =
                    (unsigned short)pk2(Eacc[mt][nt][i], 0.f);
            }

    // ================= Stage 2: S = E @ W  (hi-only) =================
    f32x4 Sacc[2][4];
    #pragma unroll
    for (int mt = 0; mt < 2; ++mt)
        #pragma unroll
        for (int nt = 0; nt < 4; ++nt) Sacc[mt][nt] = (f32x4){0.f,0.f,0.f,0.f};

    const float* wcol = W + xs_t;
    float wr[8];
    { // prologue: W chunk 0 (hi) -> buf0
        #pragma unroll
        for (int j = 0; j < 8; ++j) wr[j] = wcol[(size_t)(koct * 8 + j) * T_];
        uint2 hp;
        hp.x = pk2(wr[0],wr[1]); hp.y = pk2(wr[2],wr[3]);
        *(uint2*)(Bst[0][0] + stO) = hp;
        hp.x = pk2(wr[4],wr[5]); hp.y = pk2(wr[6],wr[7]);
        *(uint2*)(Bst[0][0] + stO + 8) = hp;
    }
    __syncthreads();   // also covers E-hi writes before A reads

    #pragma unroll 2
    for (int c = 0; c < 8; ++c) {
        const int cur = c & 1;
        if (c < 7) {
            #pragma unroll
            for (int j = 0; j < 8; ++j)
                wr[j] = wcol[(size_t)((c + 1) * 32 + koct * 8 + j) * T_];
        }
        bf16x8 Af[2];
        #pragma unroll
        for (int mt = 0; mt < 2; ++mt)
            Af[mt] = ldb128(Eh + eBase[mt] + ((c * 64 + lg * 16) ^ eSw[mt]));
        __builtin_amdgcn_s_setprio(1);
        #pragma unroll
        for (int np = 0; np < 2; ++np) {
            bf16x8 Bf[2];
            #pragma unroll
            for (int h = 0; h < 2; ++h) Bf[h] = ld16(Bst[cur][0] + bOff[np * 2 + h]);
            #pragma unroll
            for (int mt = 0; mt < 2; ++mt)
                #pragma unroll
                for (int h = 0; h < 2; ++h)
                    Sacc[mt][np*2+h] = MFMA16(Af[mt], Bf[h], Sacc[mt][np*2+h], 0,0,0);
        }
        __builtin_amdgcn_s_setprio(0);
        if (c < 7) {
            uint2 hp;
            hp.x = pk2(wr[0],wr[1]); hp.y = pk2(wr[2],wr[3]);
            *(uint2*)(Bst[cur^1][0] + stO) = hp;
            hp.x = pk2(wr[4],wr[5]); hp.y = pk2(wr[6],wr[7]);
            *(uint2*)(Bst[cur^1][0] + stO + 8) = hp;
        }
        __syncthreads();
    }

    // ============ row softmax over s (cross-wave) + blend -> Eh ============
    const float a_ = alpha[0];
    float pm[2][4];
    #pragma unroll
    for (int mt = 0; mt < 2; ++mt)
        #pragma unroll
        for (int i = 0; i < 4; ++i) {
            float m = fmaxf(fmaxf(Sacc[mt][0][i], Sacc[mt][1][i]),
                            fmaxf(Sacc[mt][2][i], Sacc[mt][3][i]));
            m = fmaxf(m, __shfl_xor(m, 1));
            m = fmaxf(m, __shfl_xor(m, 2));
            m = fmaxf(m, __shfl_xor(m, 4));
            m = fmaxf(m, __shfl_xor(m, 8));
            float s = 0.f;
            #pragma unroll
            for (int nt = 0; nt < 4; ++nt) {
                float p = __expf(Sacc[mt][nt][i] - m);
                Sacc[mt][nt][i] = p; s += p;
            }
            s += __shfl_xor(s, 1);
            s += __shfl_xor(s, 2);
            s += __shfl_xor(s, 4);
            s += __shfl_xor(s, 8);
            pm[mt][i] = m;
            if (lane16 == 0) {
                int r = wm * 32 + mt * 16 + lg * 4 + i;
                redm[wn][r] = m; reds[wn][r] = s;
            }
        }
    // issue W2 chunk-0 loads (hide under softmax finish)
    float zr[4];
    #pragma unroll
    for (int j = 0; j < 4; ++j) zr[j] = W2[(size_t)(zoct * 4 + j) * O2_ + zs];
    __syncthreads();

    #pragma unroll
    for (int mt = 0; mt < 2; ++mt)
        #pragma unroll
        for (int i = 0; i < 4; ++i) {
            int r = wm * 32 + mt * 16 + lg * 4 + i;
            float M = fmaxf(fmaxf(redm[0][r], redm[1][r]),
                            fmaxf(redm[2][r], redm[3][r]));
            float den = reds[0][r] * __expf(redm[0][r] - M)
                      + reds[1][r] * __expf(redm[1][r] - M)
                      + reds[2][r] * __expf(redm[2][r] - M)
                      + reds[3][r] * __expf(redm[3][r] - M);
            float sc = __expf(pm[mt][i] - M) / den;
            #pragma unroll
            for (int nt = 0; nt < 4; ++nt) {
                float f = a_ + (1.f - a_) * Sacc[mt][nt][i] * sc;
                float v = Eacc[mt][nt][i] * f;
                int t = wn * 64 + nt * 16 + lane16;
                *(unsigned short*)(Eh + r * 512 + ((2 * t) ^ ((r & 7) << 4))) =
                    (unsigned short)pk2(v, v);
            }
        }
    { // W2 chunk 0 convert+write (hi+lo) -> buf0
        uint2 hp, lp;
        split4(zr[0], zr[1], zr[2], zr[3], hp, lp);
        *(uint2*)(Bst[0][0] + stZ) = hp;
        *(uint2*)(Bst[0][1] + stZ) = lp;
    }
    __syncthreads();

    // ========== Stage 3: Y = blended @ W2 + bias (A-hi x (B-hi + B-lo)) ==========
    f32x4 Yacc[2][2];
    #pragma unroll
    for (int mt = 0; mt < 2; ++mt)
        #pragma unroll
        for (int nt = 0; nt < 2; ++nt) Yacc[mt][nt] = (f32x4){0.f,0.f,0.f,0.f};

    #pragma unroll 2
    for (int c = 0; c < 8; ++c) {
        const int cur = c & 1;
        if (c < 7) {
            #pragma unroll
            for (int j = 0; j < 4; ++j)
                zr[j] = W2[(size_t)((c + 1) * 32 + zoct * 4 + j) * O2_ + zs];
        }
        bf16x8 Ahf[2];
        #pragma unroll
        for (int mt = 0; mt < 2; ++mt)
            Ahf[mt] = ldb128(Eh + eBase[mt] + ((c * 64 + lg * 16) ^ eSw[mt]));
        __builtin_amdgcn_s_setprio(1);
        {
            bf16x8 Bh[2], Bl[2];
            #pragma unroll
            for (int nt = 0; nt < 2; ++nt) {
                Bh[nt] = ld16(Bst[cur][0] + b3Off[nt]);
                Bl[nt] = ld16(Bst[cur][1] + b3Off[nt]);
            }
            #pragma unroll
            for (int mt = 0; mt < 2; ++mt)
                #pragma unroll
                for (int nt = 0; nt < 2; ++nt) {
                    Yacc[mt][nt] = MFMA16(Ahf[mt], Bh[nt], Yacc[mt][nt], 0,0,0);
                    Yacc[mt][nt] = MFMA16(Ahf[mt], Bl[nt], Yacc[mt][nt], 0,0,0);
                }
        }
        __builtin_amdgcn_s_setprio(0);
        if (c < 7) {
            uint2 hp, lp;
            split4(zr[0], zr[1], zr[2], zr[3], hp, lp);
            *(uint2*)(Bst[cur^1][0] + stZ) = hp;
            *(uint2*)(Bst[cur^1][1] + stZ) = lp;
        }
        __syncthreads();
    }

    // epilogue: + bias, store pre-softmax Y
    #pragma unroll
    for (int mt = 0; mt < 2; ++mt)
        #pragma unroll
        for (int nt = 0; nt < 2; ++nt)
            #pragma unroll
            for (int i = 0; i < 4; ++i) {
                int o  = obase + wm * 32 + mt * 16 + lg * 4 + i;
                int s2 = wn * 32 + nt * 16 + lane16;
                out[((size_t)b * O1_ + o) * O2_ + s2] =
                    Yacc[mt][nt][i] + bias[(size_t)o * O2_ + s2];
            }
}

// in-place softmax over axis 1 (O1); one block per batch
__global__ __launch_bounds__(256) void softmax_o1(float* __restrict__ out)
{
    __shared__ float sm[2][128], ss[2][128];
    const int b  = blockIdx.x;
    const int s2 = threadIdx.x & 127;
    const int oh = threadIdx.x >> 7;
    float* p = out + (size_t)b * (O1_ * O2_) + s2;
    float m = -INFINITY, s = 0.f;
    #pragma unroll 4
    for (int o = oh * 128; o < oh * 128 + 128; ++o) {
        float v = p[(size_t)o * O2_];
        float mn = fmaxf(m, v);
        s = s * __expf(m - mn) + __expf(v - mn);
        m = mn;
    }
    sm[oh][s2] = m; ss[oh][s2] = s;
    __syncthreads();
    float M = fmaxf(sm[0][s2], sm[1][s2]);
    float S = ss[0][s2] * __expf(sm[0][s2] - M) + ss[1][s2] * __expf(sm[1][s2] - M);
    float inv = 1.f / S;
    #pragma unroll 4
    for (int o = oh * 128; o < oh * 128 + 128; ++o) {
        float v = p[(size_t)o * O2_];
        p[(size_t)o * O2_] = __expf(v - M) * inv;
    }
}

extern "C" void kernel_launch(void* const* d_in, const int* in_sizes, int n_in,
                              void* d_out, int out_size, void* d_ws, size_t ws_size,
                              hipStream_t stream)
{
    const float* x     = (const float*)d_in[0];
    const float* W1    = (const float*)d_in[1];
    const float* W     = (const float*)d_in[2];
    const float* W2    = (const float*)d_in[3];
    const float* alpha = (const float*)d_in[4];
    const float* bias  = (const float*)d_in[5];
    float* out = (float*)d_out;

    tabl_mfma<<<dim3(512), 1024, 0, stream>>>(x, W1, W, W2, alpha, bias, out);
    softmax_o1<<<B_, 256, 0, stream>>>(out);
}

// Round 6
// 139.782 us; speedup vs baseline: 1.9639x; 1.0222x over previous
//
#include <hip/hip_runtime.h>
#include <hip/hip_bf16.h>
#include <math.h>

#define B_   256
#define D1_  512
#define T_   256
#define O1_  256
#define O2_  128
#define OT   128

typedef __attribute__((ext_vector_type(8))) _Float16 f16x8;
typedef __attribute__((ext_vector_type(2))) _Float16 f16x2;
typedef __attribute__((ext_vector_type(4))) float f32x4;

// pack two floats -> two fp16 (RNE) in a u32 (low half = a)
__device__ inline unsigned pkh2(float a, float b) {
    union { f16x2 h; unsigned u; } c;
    c.h.x = (_Float16)a; c.h.y = (_Float16)b;
    return c.u;
}

// hi/lo fp16 split of 4 floats: hi = rne(v), lo = rne(v - hi)
__device__ inline void splith4(float v0, float v1, float v2, float v3,
                               uint2& hp, uint2& lp) {
    _Float16 h0 = (_Float16)v0, h1 = (_Float16)v1;
    _Float16 h2 = (_Float16)v2, h3 = (_Float16)v3;
    float r0 = v0 - (float)h0, r1 = v1 - (float)h1;
    float r2 = v2 - (float)h2, r3 = v3 - (float)h3;
    union { f16x2 h; unsigned u; } c;
    c.h.x = h0; c.h.y = h1; hp.x = c.u;
    c.h.x = h2; c.h.y = h3; hp.y = c.u;
    lp.x = pkh2(r0, r1); lp.y = pkh2(r2, r3);
}

// hi-only convert of 4 floats -> uint2 (4 fp16)
__device__ inline uint2 cvth4(float v0, float v1, float v2, float v3) {
    uint2 r; r.x = pkh2(v0, v1); r.y = pkh2(v2, v3); return r;
}

// 8 floats (two float4) -> fp16x8 fragment (hi only, in-register)
__device__ inline f16x8 cvt8h(float4 a, float4 b) {
    f16x8 r;
    r[0] = (_Float16)a.x; r[1] = (_Float16)a.y;
    r[2] = (_Float16)a.z; r[3] = (_Float16)a.w;
    r[4] = (_Float16)b.x; r[5] = (_Float16)b.y;
    r[6] = (_Float16)b.z; r[7] = (_Float16)b.w;
    return r;
}

// 16B fragment from 72-B-strided staging rows (two ds_read_b64)
__device__ inline f16x8 ld16(const char* p) {
    union { uint2 a[2]; f16x8 v; } f;
    f.a[0] = *(const uint2*)p;
    f.a[1] = *(const uint2*)(p + 8);
    return f.v;
}
__device__ inline f16x8 ldb128(const char* p) { return *(const f16x8*)p; }

#define MFMAH __builtin_amdgcn_mfma_f32_16x16x32_f16

// OT=128 o-rows per block, 1024 threads (16 waves, 4m x 4n), 1 block/CU,
// double-buffered staging with ONE barrier per K-chunk. fp16 hi/lo arithmetic:
// stage1 = W1h@(xh+xl) (2 MFMA), stage2 = Eh@Wh (1), stage3 = Bh@W2h (1).
__global__ __launch_bounds__(1024, 4) void tabl_mfma(
    const float* __restrict__ x, const float* __restrict__ W1,
    const float* __restrict__ W, const float* __restrict__ W2,
    const float* __restrict__ alpha, const float* __restrict__ bias,
    float* __restrict__ out)
{
    __shared__ __align__(16) char Eh[OT * 512];        // E-hi / blended-hi, XOR-swizzled
    __shared__ __align__(16) char Bst[2][2][256 * 72]; // [buf][plane hi/lo]
    __shared__ float redm[4][OT];
    __shared__ float reds[4][OT];

    const int tid    = threadIdx.x;
    const int lane16 = tid & 15;
    const int lg     = (tid >> 4) & 3;
    const int wid    = tid >> 6;          // 0..15
    const int wm     = wid >> 2;          // 0..3
    const int wn     = wid & 3;           // 0..3

    // XCD swizzle: both o-halves of a batch land on the same XCD.
    const int bi  = blockIdx.x;
    const int xcd = bi & 7, q = bi >> 3;
    const int b     = xcd + (q >> 1) * 8;
    const int obase = (q & 1) * OT;

    // staging roles
    const int xs_t = tid & 255;           // staged row (t or s)
    const int koct = tid >> 8;            // 0..3 (8 k each)
    const int stO  = xs_t * 72 + koct * 16;
    const int zs = tid & 127, zoct = (tid >> 7) & 7;   // stage-3: 4 k each
    const int stZ  = zs * 72 + zoct * 8;

    // fragment offsets
    const int rArow[2] = { obase + wm * 32 + lane16, obase + wm * 32 + 16 + lane16 };
    const int eR[2]    = { wm * 32 + lane16, wm * 32 + 16 + lane16 };
    const int eBase[2] = { eR[0] * 512, eR[1] * 512 };
    const int eSw[2]   = { (eR[0] & 7) << 4, (eR[1] & 7) << 4 };
    int bOff[4], b3Off[2];
    #pragma unroll
    for (int nt = 0; nt < 4; ++nt) bOff[nt] = (wn * 64 + nt * 16 + lane16) * 72 + lg * 16;
    #pragma unroll
    for (int nt = 0; nt < 2; ++nt) b3Off[nt] = (wn * 32 + nt * 16 + lane16) * 72 + lg * 16;

    // ================= Stage 1: E = W1h @ (xh + xl)  (2-term fp16) =================
    f32x4 Eacc[2][4];
    #pragma unroll
    for (int mt = 0; mt < 2; ++mt)
        #pragma unroll
        for (int nt = 0; nt < 4; ++nt) Eacc[mt][nt] = (f32x4){0.f,0.f,0.f,0.f};

    const float* xcol = x + (size_t)b * (D1_ * T_) + xs_t;
    float xr[8]; float4 apf[2][2];

    { // prologue: x chunk 0 -> buf0; A chunk 0 -> regs
        #pragma unroll
        for (int j = 0; j < 8; ++j) xr[j] = xcol[(size_t)(koct * 8 + j) * T_];
        #pragma unroll
        for (int mt = 0; mt < 2; ++mt) {
            const float4* ap = (const float4*)(W1 + (size_t)rArow[mt] * D1_ + lg * 8);
            apf[mt][0] = ap[0]; apf[mt][1] = ap[1];
        }
        uint2 hp, lp;
        splith4(xr[0],xr[1],xr[2],xr[3],hp,lp);
        *(uint2*)(Bst[0][0] + stO) = hp; *(uint2*)(Bst[0][1] + stO) = lp;
        splith4(xr[4],xr[5],xr[6],xr[7],hp,lp);
        *(uint2*)(Bst[0][0] + stO + 8) = hp; *(uint2*)(Bst[0][1] + stO + 8) = lp;
    }
    __syncthreads();

    #pragma unroll 2
    for (int c = 0; c < 16; ++c) {
        const int cur = c & 1;
        // (1) issue x loads for c+1
        if (c < 15) {
            #pragma unroll
            for (int j = 0; j < 8; ++j)
                xr[j] = xcol[(size_t)((c + 1) * 32 + koct * 8 + j) * T_];
        }
        // (2) convert current A regs -> fp16 fragments (hi only)
        f16x8 Ah[2];
        #pragma unroll
        for (int mt = 0; mt < 2; ++mt) Ah[mt] = cvt8h(apf[mt][0], apf[mt][1]);
        // (3) issue A loads for c+1
        if (c < 15) {
            #pragma unroll
            for (int mt = 0; mt < 2; ++mt) {
                const float4* ap = (const float4*)(W1 + (size_t)rArow[mt] * D1_ + (c + 1) * 32 + lg * 8);
                apf[mt][0] = ap[0]; apf[mt][1] = ap[1];
            }
        }
        // (4) B fragments + MFMA (nt-paired to limit registers)
        __builtin_amdgcn_s_setprio(1);
        #pragma unroll
        for (int np = 0; np < 2; ++np) {
            f16x8 Bh[2], Bl[2];
            #pragma unroll
            for (int h = 0; h < 2; ++h) {
                Bh[h] = ld16(Bst[cur][0] + bOff[np * 2 + h]);
                Bl[h] = ld16(Bst[cur][1] + bOff[np * 2 + h]);
            }
            #pragma unroll
            for (int mt = 0; mt < 2; ++mt)
                #pragma unroll
                for (int h = 0; h < 2; ++h) {
                    Eacc[mt][np*2+h] = MFMAH(Ah[mt], Bh[h], Eacc[mt][np*2+h], 0,0,0);
                    Eacc[mt][np*2+h] = MFMAH(Ah[mt], Bl[h], Eacc[mt][np*2+h], 0,0,0);
                }
        }
        __builtin_amdgcn_s_setprio(0);
        // (5) convert + write chunk c+1 into the other buffer
        if (c < 15) {
            uint2 hp, lp;
            splith4(xr[0],xr[1],xr[2],xr[3],hp,lp);
            *(uint2*)(Bst[cur^1][0] + stO) = hp; *(uint2*)(Bst[cur^1][1] + stO) = lp;
            splith4(xr[4],xr[5],xr[6],xr[7],hp,lp);
            *(uint2*)(Bst[cur^1][0] + stO + 8) = hp; *(uint2*)(Bst[cur^1][1] + stO + 8) = lp;
        }
        __syncthreads();
    }

    // write E-hi (fp16) to LDS for stage-2/3 A fragments (E stays in regs for blend)
    #pragma unroll
    for (int mt = 0; mt < 2; ++mt)
        #pragma unroll
        for (int nt = 0; nt < 4; ++nt)
            #pragma unroll
            for (int i = 0; i < 4; ++i) {
                int r = wm * 32 + mt * 16 + lg * 4 + i;
                int t = wn * 64 + nt * 16 + lane16;
                union { _Float16 h; unsigned short u; } cc;
                cc.h = (_Float16)Eacc[mt][nt][i];
                *(unsigned short*)(Eh + r * 512 + ((2 * t) ^ ((r & 7) << 4))) = cc.u;
            }

    // ================= Stage 2: S = Eh @ Wh  (fp16 hi-only) =================
    f32x4 Sacc[2][4];
    #pragma unroll
    for (int mt = 0; mt < 2; ++mt)
        #pragma unroll
        for (int nt = 0; nt < 4; ++nt) Sacc[mt][nt] = (f32x4){0.f,0.f,0.f,0.f};

    const float* wcol = W + xs_t;
    float wr[8];
    { // prologue: W chunk 0 (hi) -> buf0
        #pragma unroll
        for (int j = 0; j < 8; ++j) wr[j] = wcol[(size_t)(koct * 8 + j) * T_];
        *(uint2*)(Bst[0][0] + stO)     = cvth4(wr[0],wr[1],wr[2],wr[3]);
        *(uint2*)(Bst[0][0] + stO + 8) = cvth4(wr[4],wr[5],wr[6],wr[7]);
    }
    __syncthreads();   // also covers E-hi writes before A reads

    #pragma unroll 2
    for (int c = 0; c < 8; ++c) {
        const int cur = c & 1;
        if (c < 7) {
            #pragma unroll
            for (int j = 0; j < 8; ++j)
                wr[j] = wcol[(size_t)((c + 1) * 32 + koct * 8 + j) * T_];
        }
        f16x8 Af[2];
        #pragma unroll
        for (int mt = 0; mt < 2; ++mt)
            Af[mt] = ldb128(Eh + eBase[mt] + ((c * 64 + lg * 16) ^ eSw[mt]));
        __builtin_amdgcn_s_setprio(1);
        #pragma unroll
        for (int np = 0; np < 2; ++np) {
            f16x8 Bf[2];
            #pragma unroll
            for (int h = 0; h < 2; ++h) Bf[h] = ld16(Bst[cur][0] + bOff[np * 2 + h]);
            #pragma unroll
            for (int mt = 0; mt < 2; ++mt)
                #pragma unroll
                for (int h = 0; h < 2; ++h)
                    Sacc[mt][np*2+h] = MFMAH(Af[mt], Bf[h], Sacc[mt][np*2+h], 0,0,0);
        }
        __builtin_amdgcn_s_setprio(0);
        if (c < 7) {
            *(uint2*)(Bst[cur^1][0] + stO)     = cvth4(wr[0],wr[1],wr[2],wr[3]);
            *(uint2*)(Bst[cur^1][0] + stO + 8) = cvth4(wr[4],wr[5],wr[6],wr[7]);
        }
        __syncthreads();
    }

    // ============ row softmax over s (cross-wave) + blend -> Eh ============
    const float a_ = alpha[0];
    float pm[2][4];
    #pragma unroll
    for (int mt = 0; mt < 2; ++mt)
        #pragma unroll
        for (int i = 0; i < 4; ++i) {
            float m = fmaxf(fmaxf(Sacc[mt][0][i], Sacc[mt][1][i]),
                            fmaxf(Sacc[mt][2][i], Sacc[mt][3][i]));
            m = fmaxf(m, __shfl_xor(m, 1));
            m = fmaxf(m, __shfl_xor(m, 2));
            m = fmaxf(m, __shfl_xor(m, 4));
            m = fmaxf(m, __shfl_xor(m, 8));
            float s = 0.f;
            #pragma unroll
            for (int nt = 0; nt < 4; ++nt) {
                float p = __expf(Sacc[mt][nt][i] - m);
                Sacc[mt][nt][i] = p; s += p;
            }
            s += __shfl_xor(s, 1);
            s += __shfl_xor(s, 2);
            s += __shfl_xor(s, 4);
            s += __shfl_xor(s, 8);
            pm[mt][i] = m;
            if (lane16 == 0) {
                int r = wm * 32 + mt * 16 + lg * 4 + i;
                redm[wn][r] = m; reds[wn][r] = s;
            }
        }
    // issue W2 chunk-0 loads (hide under softmax finish)
    float zr[4];
    #pragma unroll
    for (int j = 0; j < 4; ++j) zr[j] = W2[(size_t)(zoct * 4 + j) * O2_ + zs];
    __syncthreads();

    #pragma unroll
    for (int mt = 0; mt < 2; ++mt)
        #pragma unroll
        for (int i = 0; i < 4; ++i) {
            int r = wm * 32 + mt * 16 + lg * 4 + i;
            float M = fmaxf(fmaxf(redm[0][r], redm[1][r]),
                            fmaxf(redm[2][r], redm[3][r]));
            float den = reds[0][r] * __expf(redm[0][r] - M)
                      + reds[1][r] * __expf(redm[1][r] - M)
                      + reds[2][r] * __expf(redm[2][r] - M)
                      + reds[3][r] * __expf(redm[3][r] - M);
            float sc = __expf(pm[mt][i] - M) / den;
            #pragma unroll
            for (int nt = 0; nt < 4; ++nt) {
                float f = a_ + (1.f - a_) * Sacc[mt][nt][i] * sc;
                float v = Eacc[mt][nt][i] * f;
                int t = wn * 64 + nt * 16 + lane16;
                union { _Float16 h; unsigned short u; } cc;
                cc.h = (_Float16)v;
                *(unsigned short*)(Eh + r * 512 + ((2 * t) ^ ((r & 7) << 4))) = cc.u;
            }
        }
    { // W2 chunk 0 convert+write (hi only) -> buf0
        *(uint2*)(Bst[0][0] + stZ) = cvth4(zr[0], zr[1], zr[2], zr[3]);
    }
    __syncthreads();

    // ========== Stage 3: Y = blended_h @ W2h + bias (fp16 hi-only) ==========
    f32x4 Yacc[2][2];
    #pragma unroll
    for (int mt = 0; mt < 2; ++mt)
        #pragma unroll
        for (int nt = 0; nt < 2; ++nt) Yacc[mt][nt] = (f32x4){0.f,0.f,0.f,0.f};

    #pragma unroll 2
    for (int c = 0; c < 8; ++c) {
        const int cur = c & 1;
        if (c < 7) {
            #pragma unroll
            for (int j = 0; j < 4; ++j)
                zr[j] = W2[(size_t)((c + 1) * 32 + zoct * 4 + j) * O2_ + zs];
        }
        f16x8 Ahf[2];
        #pragma unroll
        for (int mt = 0; mt < 2; ++mt)
            Ahf[mt] = ldb128(Eh + eBase[mt] + ((c * 64 + lg * 16) ^ eSw[mt]));
        __builtin_amdgcn_s_setprio(1);
        {
            f16x8 Bh[2];
            #pragma unroll
            for (int nt = 0; nt < 2; ++nt) Bh[nt] = ld16(Bst[cur][0] + b3Off[nt]);
            #pragma unroll
            for (int mt = 0; mt < 2; ++mt)
                #pragma unroll
                for (int nt = 0; nt < 2; ++nt)
                    Yacc[mt][nt] = MFMAH(Ahf[mt], Bh[nt], Yacc[mt][nt], 0,0,0);
        }
        __builtin_amdgcn_s_setprio(0);
        if (c < 7) {
            *(uint2*)(Bst[cur^1][0] + stZ) = cvth4(zr[0], zr[1], zr[2], zr[3]);
        }
        __syncthreads();
    }

    // epilogue: + bias, store pre-softmax Y
    #pragma unroll
    for (int mt = 0; mt < 2; ++mt)
        #pragma unroll
        for (int nt = 0; nt < 2; ++nt)
            #pragma unroll
            for (int i = 0; i < 4; ++i) {
                int o  = obase + wm * 32 + mt * 16 + lg * 4 + i;
                int s2 = wn * 32 + nt * 16 + lane16;
                out[((size_t)b * O1_ + o) * O2_ + s2] =
                    Yacc[mt][nt][i] + bias[(size_t)o * O2_ + s2];
            }
}

// in-place softmax over axis 1 (O1); one block per batch
__global__ __launch_bounds__(256) void softmax_o1(float* __restrict__ out)
{
    __shared__ float sm[2][128], ss[2][128];
    const int b  = blockIdx.x;
    const int s2 = threadIdx.x & 127;
    const int oh = threadIdx.x >> 7;
    float* p = out + (size_t)b * (O1_ * O2_) + s2;
    float m = -INFINITY, s = 0.f;
    #pragma unroll 4
    for (int o = oh * 128; o < oh * 128 + 128; ++o) {
        float v = p[(size_t)o * O2_];
        float mn = fmaxf(m, v);
        s = s * __expf(m - mn) + __expf(v - mn);
        m = mn;
    }
    sm[oh][s2] = m; ss[oh][s2] = s;
    __syncthreads();
    float M = fmaxf(sm[0][s2], sm[1][s2]);
    float S = ss[0][s2] * __expf(sm[0][s2] - M) + ss[1][s2] * __expf(sm[1][s2] - M);
    float inv = 1.f / S;
    #pragma unroll 4
    for (int o = oh * 128; o < oh * 128 + 128; ++o) {
        float v = p[(size_t)o * O2_];
        p[(size_t)o * O2_] = __expf(v - M) * inv;
    }
}

extern "C" void kernel_launch(void* const* d_in, const int* in_sizes, int n_in,
                              void* d_out, int out_size, void* d_ws, size_t ws_size,
                              hipStream_t stream)
{
    const float* x     = (const float*)d_in[0];
    const float* W1    = (const float*)d_in[1];
    const float* W     = (const float*)d_in[2];
    const float* W2    = (const float*)d_in[3];
    const float* alpha = (const float*)d_in[4];
    const float* bias  = (const float*)d_in[5];
    float* out = (float*)d_out;

    tabl_mfma<<<dim3(512), 1024, 0, stream>>>(x, W1, W, W2, alpha, bias, out);
    softmax_o1<<<B_, 256, 0, stream>>>(out);
}